// Round 6
// baseline (1316.228 us; speedup 1.0000x reference)
//
#include <hip/hip_runtime.h>

#define B 128
#define T 1500
#define NI 80        // N_MELS
#define H 128        // HIDDEN
#define G 384        // 3*H
#define TT 64        // t-tile for gx gemm
#define TS 16        // gx tile (steps) staged in LDS by scan

typedef float v2f __attribute__((ext_vector_type(2)));

__device__ __forceinline__ float sigf(float x) { return 1.0f / (1.0f + __expf(-x)); }
__device__ __forceinline__ float tanhfast(float x) { return 1.0f - 2.0f / (1.0f + __expf(2.0f * x)); }
__device__ __forceinline__ v2f pkfma(v2f a, v2f b, v2f c) { return __builtin_elementwise_fma(a, b, c); }

// quad butterfly sum over lanes xor 1, xor 2 — explicit DPP quad_perm (VALU pipe, no LDS)
__device__ __forceinline__ float qsum(float v) {
    int a = __builtin_bit_cast(int, v);
    int b = __builtin_amdgcn_update_dpp(0, a, 0xB1, 0xF, 0xF, true);   // quad_perm [1,0,3,2]
    float s = v + __builtin_bit_cast(float, b);
    int c = __builtin_bit_cast(int, s);
    int d = __builtin_amdgcn_update_dpp(0, c, 0x4E, 0xF, 0xF, true);   // quad_perm [2,3,0,1]
    return s + __builtin_bit_cast(float, d);
}

// ---------------- gx GEMM (unchanged from round 4: 285us, known-good) ----------------
__global__ __launch_bounds__(384)
void gx_gemm_kernel(const float* __restrict__ x, const float* __restrict__ w_ih,
                    const float* __restrict__ b_ih, float* __restrict__ gx,
                    int t0, int ct) {
    int tile = blockIdx.x;
    int b = blockIdx.y;
    int tl0 = tile * TT;
    if (tl0 >= ct) return;
    int n = (ct - tl0 < TT) ? (ct - tl0) : TT;
    int tid = threadIdx.x;  // = output g

    __shared__ __align__(16) float xs[TT * NI];   // 20 KB
    const float4* xsrc4 = (const float4*)(x + ((size_t)b * T + (size_t)(t0 + tl0)) * NI);
    int total4 = n * (NI / 4);
    for (int i = tid; i < total4; i += 384) ((float4*)xs)[i] = xsrc4[i];

    v2f w2[40];
    const v2f* wr = (const v2f*)(w_ih + (size_t)tid * NI);
#pragma unroll
    for (int i = 0; i < 40; ++i) w2[i] = wr[i];
    float bias = b_ih[tid];
    __syncthreads();

    float* gout = gx + ((size_t)b * ct + (size_t)tl0) * G + tid;
    int tt = 0;
    for (; tt + 2 <= n; tt += 2) {
        const float4* xa4 = (const float4*)(xs + tt * NI);
        const float4* xb4 = (const float4*)(xs + (tt + 1) * NI);
        v2f a0 = {0.f, 0.f}, a1 = {0.f, 0.f}, c0 = {0.f, 0.f}, c1 = {0.f, 0.f};
#pragma unroll
        for (int i = 0; i < 20; ++i) {
            float4 xa = xa4[i];
            float4 xb = xb4[i];
            v2f alo = {xa.x, xa.y}, ahi = {xa.z, xa.w};
            v2f blo = {xb.x, xb.y}, bhi = {xb.z, xb.w};
            a0 = pkfma(w2[2 * i], alo, a0);
            a1 = pkfma(w2[2 * i + 1], ahi, a1);
            c0 = pkfma(w2[2 * i], blo, c0);
            c1 = pkfma(w2[2 * i + 1], bhi, c1);
        }
        gout[(size_t)tt * G]       = bias + ((a0.x + a0.y) + (a1.x + a1.y));
        gout[(size_t)(tt + 1) * G] = bias + ((c0.x + c0.y) + (c1.x + c1.y));
    }
    if (tt < n) {
        const float4* xa4 = (const float4*)(xs + tt * NI);
        v2f a0 = {0.f, 0.f}, a1 = {0.f, 0.f};
#pragma unroll
        for (int i = 0; i < 20; ++i) {
            float4 xa = xa4[i];
            v2f alo = {xa.x, xa.y}, ahi = {xa.z, xa.w};
            a0 = pkfma(w2[2 * i], alo, a0);
            a1 = pkfma(w2[2 * i + 1], ahi, a1);
        }
        gout[(size_t)tt * G] = bias + ((a0.x + a0.y) + (a1.x + a1.y));
    }
}

// ---------------- scan ----------------
// 512 threads: tid = j*4 + q. W_hh rows {j,j+H,j+2H} k-slice [32q,32q+32) in VGPRs (packed).
// gx consumed from LDS: 16-step tiles, double-buffered, cooperatively loaded with
// coalesced dwordx4 (3/thread/tile) issued one full tile ahead (latency ~15K cyc hidden).
// Per step: 8 ds_read_b128 (h) + 3 broadcast ds_read_b32 (gx), 48 pk_fma, DPP quad
// reduce, gates, h write to LDS double buffer. Raw s_barrier + lgkmcnt-only wait.
__global__ __launch_bounds__(512)
void scan_kernel(const float* __restrict__ gx, const float* __restrict__ w_hh,
                 const float* __restrict__ b_hh, float* __restrict__ h_state,
                 int ct, int first, int last,
                 const float* __restrict__ x,
                 const float* __restrict__ w_ih_b, const float* __restrict__ b_ih_b,
                 const float* __restrict__ b_hh_b,
                 const float* __restrict__ w1, const float* __restrict__ b1,
                 const float* __restrict__ w2, const float* __restrict__ b2,
                 float* __restrict__ out) {
    int b = blockIdx.x;
    int tid = threadIdx.x;
    int j = tid >> 2;
    int q = tid & 3;
    int jpad = j + ((j >> 5) << 2);   // padded h index (36-float q-slice stride)

    __shared__ __align__(16) float hs0[144];
    __shared__ __align__(16) float hs1[144];
    __shared__ __align__(16) float gxs[2][TS * G];   // 2 x 24.5 KB
    __shared__ __align__(16) float tail_gx[G];
    __shared__ __align__(16) float last_s[2 * H];
    __shared__ __align__(16) float xb_s[NI];

    // W_hh fragments (packed)
    v2f WR[16], WZ[16], WN[16];
    {
        const v2f* p0 = (const v2f*)(w_hh + (size_t)j * H + 32 * q);
        const v2f* p1 = (const v2f*)(w_hh + (size_t)(j + H) * H + 32 * q);
        const v2f* p2 = (const v2f*)(w_hh + (size_t)(j + 2 * H) * H + 32 * q);
#pragma unroll
        for (int i = 0; i < 16; ++i) { WR[i] = p0[i]; WZ[i] = p1[i]; WN[i] = p2[i]; }
    }
    float br = b_hh[j], bz = b_hh[j + H], bn = b_hh[j + 2 * H];

    // ---- gx tile staging prologue: tile0 -> LDS, tile1 -> regs ----
    const float4* gsrc4 = (const float4*)(gx + (size_t)b * ct * G);
    size_t limit4 = (size_t)ct * (G / 4) - 1;
    float4 gr[3];
#pragma unroll
    for (int i = 0; i < 3; ++i) {
        size_t idx = (size_t)i * 512 + tid; if (idx > limit4) idx = limit4;
        gr[i] = gsrc4[idx];
    }
    {
        float4* d4 = (float4*)gxs[0];
#pragma unroll
        for (int i = 0; i < 3; ++i) d4[(size_t)i * 512 + tid] = gr[i];
    }
#pragma unroll
    for (int i = 0; i < 3; ++i) {
        size_t idx = (size_t)(TS * G / 4) + (size_t)i * 512 + tid; if (idx > limit4) idx = limit4;
        gr[i] = gsrc4[idx];
    }

    float h_cur = 0.f;
    if (!first) h_cur = h_state[b * H + j];
    if (q == 0) hs0[jpad] = h_cur;
    __syncthreads();   // prologue only

    float* hsrc = hs0;
    float* hdst = hs1;
    int ntiles = (ct + TS - 1) / TS;

    for (int c = 0; c < ntiles; ++c) {
        int ns = (ct - c * TS < TS) ? (ct - c * TS) : TS;
        const float* gtile = gxs[c & 1];
        for (int s = 0; s < ns; ++s) {
            float g0 = gtile[s * G + j];
            float g1 = gtile[s * G + j + H];
            float g2 = gtile[s * G + j + 2 * H];
            const float4* hv4 = (const float4*)(hsrc + 36 * q);
            v2f arv = {0.f, 0.f}, azv = {0.f, 0.f}, anv = {0.f, 0.f};
#pragma unroll
            for (int i = 0; i < 8; ++i) {
                float4 hv = hv4[i];
                v2f hlo = {hv.x, hv.y}, hhi = {hv.z, hv.w};
                arv = pkfma(WR[2 * i], hlo, arv);
                azv = pkfma(WZ[2 * i], hlo, azv);
                anv = pkfma(WN[2 * i], hlo, anv);
                arv = pkfma(WR[2 * i + 1], hhi, arv);
                azv = pkfma(WZ[2 * i + 1], hhi, azv);
                anv = pkfma(WN[2 * i + 1], hhi, anv);
            }
            float ar = qsum(arv.x + arv.y);
            float az = qsum(azv.x + azv.y);
            float an = qsum(anv.x + anv.y);
            float r = sigf(g0 + br + ar);
            float z = sigf(g1 + bz + az);
            float n = tanhfast(g2 + r * (bn + an));
            h_cur = (1.f - z) * n + z * h_cur;
            if (q == 0) hdst[jpad] = h_cur;
            float* tmp = hsrc; hsrc = hdst; hdst = tmp;
            asm volatile("s_waitcnt lgkmcnt(0)\n\ts_barrier" ::: "memory");
        }
        // stage tile c+1 (regs -> LDS), prefetch tile c+2 (global -> regs)
        if (c + 1 < ntiles) {
            float4* d4 = (float4*)gxs[(c + 1) & 1];
#pragma unroll
            for (int i = 0; i < 3; ++i) d4[(size_t)i * 512 + tid] = gr[i];
            if (c + 2 < ntiles) {
#pragma unroll
                for (int i = 0; i < 3; ++i) {
                    size_t idx = (size_t)(c + 2) * (TS * G / 4) + (size_t)i * 512 + tid;
                    if (idx > limit4) idx = limit4;
                    gr[i] = gsrc4[idx];
                }
            }
            asm volatile("s_waitcnt lgkmcnt(0)\n\ts_barrier" ::: "memory");
        }
    }

    if (!last) {
        if (q == 0) h_state[b * H + j] = h_cur;
        return;
    }

    // ---- backward single step (h0 = 0) + MLP head ----
    if (tid < NI) xb_s[tid] = x[((size_t)b * T + (T - 1)) * NI + tid];
    if (q == 0) last_s[j] = h_cur;  // forward final hidden
    __syncthreads();

    if (tid < G) {
        const float4* wbr = (const float4*)(w_ih_b + (size_t)tid * NI);
        const float4* xv = (const float4*)xb_s;
        float a0 = 0.f, a1 = 0.f, a2 = 0.f, a3 = 0.f;
#pragma unroll
        for (int i = 0; i < 20; ++i) {
            float4 wv = wbr[i]; float4 x4 = xv[i];
            a0 = fmaf(wv.x, x4.x, a0); a1 = fmaf(wv.y, x4.y, a1);
            a2 = fmaf(wv.z, x4.z, a2); a3 = fmaf(wv.w, x4.w, a3);
        }
        tail_gx[tid] = b_ih_b[tid] + ((a0 + a1) + (a2 + a3));
    }
    __syncthreads();

    if (tid < H) {
        float r = sigf(tail_gx[tid] + b_hh_b[tid]);
        float z = sigf(tail_gx[tid + H] + b_hh_b[tid + H]);
        float n = tanhfast(tail_gx[tid + 2 * H] + r * b_hh_b[tid + 2 * H]);
        last_s[H + tid] = (1.f - z) * n;  // + z*0
    }
    __syncthreads();

    if (tid < 64) {
        const float4* w1r = (const float4*)(w1 + (size_t)tid * 2 * H);
        const float4* lv = (const float4*)last_s;
        float a0 = 0.f, a1 = 0.f, a2 = 0.f, a3 = 0.f;
#pragma unroll
        for (int i = 0; i < 64; ++i) {
            float4 wv = w1r[i]; float4 l4 = lv[i];
            a0 = fmaf(wv.x, l4.x, a0); a1 = fmaf(wv.y, l4.y, a1);
            a2 = fmaf(wv.z, l4.z, a2); a3 = fmaf(wv.w, l4.w, a3);
        }
        float v = b1[tid] + ((a0 + a1) + (a2 + a3));
        v = fmaxf(v, 0.f) * w2[tid];
#pragma unroll
        for (int off = 32; off > 0; off >>= 1) v += __shfl_down(v, off);
        if (tid == 0) out[b] = v + b2[0];
    }
}

extern "C" void kernel_launch(void* const* d_in, const int* in_sizes, int n_in,
                              void* d_out, int out_size, void* d_ws, size_t ws_size,
                              hipStream_t stream) {
    (void)in_sizes; (void)n_in; (void)out_size;
    const float* x      = (const float*)d_in[0];
    const float* w_ih_f = (const float*)d_in[1];
    const float* w_hh_f = (const float*)d_in[2];
    const float* b_ih_f = (const float*)d_in[3];
    const float* b_hh_f = (const float*)d_in[4];
    const float* w_ih_b = (const float*)d_in[5];
    const float* w_hh_b = (const float*)d_in[6];  // unused: h0=0 makes gh_b = b_hh_b
    const float* b_ih_b = (const float*)d_in[7];
    const float* b_hh_b = (const float*)d_in[8];
    const float* w1     = (const float*)d_in[9];
    const float* b1     = (const float*)d_in[10];
    const float* w2     = (const float*)d_in[11];
    const float* b2     = (const float*)d_in[12];
    (void)w_hh_b;
    float* out = (float*)d_out;

    float* h_state = (float*)d_ws;                 // B*H floats
    float* gxbuf = h_state + B * H;
    size_t hbytes = (size_t)B * H * sizeof(float);
    size_t avail = ws_size > hbytes ? ws_size - hbytes : 0;
    long long chunkT = (long long)(avail / ((size_t)B * G * sizeof(float)));
    if (chunkT > T) chunkT = T;
    if (chunkT < 1) chunkT = 1;

    for (int t0 = 0; t0 < T; t0 += (int)chunkT) {
        int ct = (T - t0 < (int)chunkT) ? (T - t0) : (int)chunkT;
        int ntiles = (ct + TT - 1) / TT;
        gx_gemm_kernel<<<dim3(ntiles, B), dim3(384), 0, stream>>>(
            x, w_ih_f, b_ih_f, gxbuf, t0, ct);
        scan_kernel<<<dim3(B), dim3(512), 0, stream>>>(
            gxbuf, w_hh_f, b_hh_f, h_state, ct,
            (t0 == 0) ? 1 : 0, (t0 + ct >= T) ? 1 : 0,
            x, w_ih_b, b_ih_b, b_hh_b, w1, b1, w2, b2, out);
    }
}